// Round 1
// baseline (358.532 us; speedup 1.0000x reference)
//
#include <hip/hip_runtime.h>

#define B 8
#define H 160
#define W 160
#define D 96
#define S 64
#define ST_RATIO 1.5f

// Each block: 256 threads = 4 (b,h,w) positions x 64 slices.
// Output layout [B,H,W,S]: lane (tid&63) = s -> fully coalesced writes.
__global__ __launch_bounds__(256) void v2s_kernel(
    const float* __restrict__ vol,   // [B,H,W,D]
    const float* __restrict__ trf,   // [B,S,12]
    float* __restrict__ out)         // [B,H,W,S]
{
    __shared__ float As[S * 13];     // stride 13: avoids 8-way bank conflict of stride 12

    const int pos0 = blockIdx.x * 4;          // linear (b*H+h)*W+w base; H*W divisible by 4
    const int b = pos0 / (H * W);             // same b for all 4 positions in block

    // Stage A = trf[b] + eye(4)[:3,:] into LDS
    const float* tb = trf + (size_t)b * S * 12;
    for (int e = threadIdx.x; e < S * 12; e += 256) {
        int s = e / 12, j = e - s * 12;
        float v = tb[e];
        if ((j & 3) == (j >> 2)) v += 1.0f;   // diagonal: j in {0,5,10}
        As[s * 13 + j] = v;
    }
    __syncthreads();

    const int s   = threadIdx.x & 63;
    const int pos = pos0 + (threadIdx.x >> 6);
    const int hw  = pos % (H * W);
    const int h   = hw / W;
    const int w   = hw - h * W;

    const float* a = &As[s * 13];
    const float fh = (float)h, fw = (float)w, fz = (float)s * ST_RATIO;

    float x = fmaf(a[0], fh, fmaf(a[1], fw, fmaf(a[2],  fz, a[3])));
    float y = fmaf(a[4], fh, fmaf(a[5], fw, fmaf(a[6],  fz, a[7])));
    float z = fmaf(a[8], fh, fmaf(a[9], fw, fmaf(a[10], fz, a[11])));

    // border clip (matches reference: clip float loc, then floor)
    x = fminf(fmaxf(x, 0.0f), (float)(H - 1));
    y = fminf(fmaxf(y, 0.0f), (float)(W - 1));
    z = fminf(fmaxf(z, 0.0f), (float)(D - 1));

    const float flx = floorf(x), fly = floorf(y), flz = floorf(z);
    const float dx = x - flx, dy = y - fly, dz = z - flz;
    const int ix0 = (int)flx, iy0 = (int)fly, iz0 = (int)flz;
    const int ix1 = min(ix0 + 1, H - 1);
    const int iy1 = min(iy0 + 1, W - 1);
    const int iz1 = min(iz0 + 1, D - 1);

    const float* vb  = vol + (size_t)b * (H * W * D);
    const float* p00 = vb + (ix0 * W + iy0) * D;
    const float* p01 = vb + (ix0 * W + iy1) * D;
    const float* p10 = vb + (ix1 * W + iy0) * D;
    const float* p11 = vb + (ix1 * W + iy1) * D;

    const float v000 = p00[iz0], v001 = p00[iz1];
    const float v010 = p01[iz0], v011 = p01[iz1];
    const float v100 = p10[iz0], v101 = p10[iz1];
    const float v110 = p11[iz0], v111 = p11[iz1];

    // trilinear via lerps (7 lerps)
    const float c00 = fmaf(dz, v001 - v000, v000);
    const float c01 = fmaf(dz, v011 - v010, v010);
    const float c10 = fmaf(dz, v101 - v100, v100);
    const float c11 = fmaf(dz, v111 - v110, v110);
    const float c0  = fmaf(dy, c01 - c00, c00);
    const float c1  = fmaf(dy, c11 - c10, c10);
    const float res = fmaf(dx, c1 - c0, c0);

    out[(size_t)pos * S + s] = res;
}

extern "C" void kernel_launch(void* const* d_in, const int* in_sizes, int n_in,
                              void* d_out, int out_size, void* d_ws, size_t ws_size,
                              hipStream_t stream) {
    const float* vol = (const float*)d_in[0];
    const float* trf = (const float*)d_in[1];
    float* out = (float*)d_out;

    const int total_pos = B * H * W;          // 204800
    const int grid = total_pos / 4;           // 51200 blocks, 256 threads each
    v2s_kernel<<<grid, 256, 0, stream>>>(vol, trf, out);
}

// Round 2
// 188.149 us; speedup vs baseline: 1.9056x; 1.9056x over previous
//
#include <hip/hip_runtime.h>
#include <hip/hip_fp16.h>

#define B 8
#define H 160
#define W 160
#define D 96
#define S 64
#define ST_RATIO 1.5f

// ---------------------------------------------------------------------------
// Pass 1: transpose vol [B,H,W,D] f32 -> volT [B,H,D,W] fp16.
// W becomes the fastest axis so in-plane-contiguous waves gather contiguously.
// ---------------------------------------------------------------------------
__global__ __launch_bounds__(256) void v2s_transpose(
    const float* __restrict__ vol, __half* __restrict__ volT)
{
    __shared__ float t[32][33];
    const int blk = blockIdx.x;          // B*H*5*3 = 19200 blocks
    const int bh  = blk / 15;
    const int rem = blk - bh * 15;
    const int wt  = rem / 3;             // W tile (5 of 32)
    const int dt  = rem - wt * 3;        // D tile (3 of 32)
    const float* in  = vol  + (size_t)bh * (W * D);
    __half*      op  = volT + (size_t)bh * (D * W);
    const int tx = threadIdx.x & 31, ty = threadIdx.x >> 5;   // ty 0..7
#pragma unroll
    for (int r = 0; r < 4; ++r) {        // coalesced read along D
        const int w_ = wt * 32 + ty + 8 * r;
        const int d_ = dt * 32 + tx;
        t[ty + 8 * r][tx] = in[w_ * D + d_];
    }
    __syncthreads();
#pragma unroll
    for (int r = 0; r < 4; ++r) {        // coalesced write along W
        const int d_ = dt * 32 + ty + 8 * r;
        const int w_ = wt * 32 + tx;
        op[d_ * W + w_] = __float2half(t[tx][ty + 8 * r]);
    }
}

// ---------------------------------------------------------------------------
// Pass 2: sampling. Block = 64 consecutive (h,w) positions x all 64 slices.
// Wave = 64 hw-lanes at ONE s (A-matrix wave-uniform; y ~ w+lane -> gathers
// are near-contiguous runs in the [B,H,D,W] fp16 volume). Output staged in
// LDS and written back with lanes along s (coalesced, matches [B,H,W,S]).
// ---------------------------------------------------------------------------
__global__ __launch_bounds__(256) void v2s_main(
    const __half* __restrict__ volT,   // [B,H,D,W]
    const float*  __restrict__ trf,    // [B,S,12]
    float*        __restrict__ out)    // [B,H,W,S]
{
    __shared__ float As[S * 12];
    __shared__ float outT[64][65];     // [hw_lane][s], pad 65: conflict-free both ways

    // XCD-aware swizzle: 3200 tiles = 8 batches x 400 -> each XCD owns one batch
    const int bid  = blockIdx.x;
    const int tile = (bid & 7) * 400 + (bid >> 3);
    const int b    = tile / 400;                 // batch
    const int hw0  = (tile - b * 400) * 64;      // in-batch linear hw base

    // Stage A = trf[b] + eye(4)[:3,:]
    const float* tb = trf + (size_t)b * (S * 12);
    for (int e = threadIdx.x; e < S * 12; e += 256) {
        const int j = e % 12;
        float v = tb[e];
        if ((j & 3) == (j >> 2)) v += 1.0f;      // diagonal j in {0,5,10}
        As[e] = v;
    }
    __syncthreads();

    const int lane = threadIdx.x & 63;
    const int wid  = threadIdx.x >> 6;
    const int hw   = hw0 + lane;
    const int h    = hw / W;
    const int w    = hw - h * W;
    const float fh = (float)h, fw = (float)w;
    const __half* vb = volT + (size_t)b * (H * D * W);

#pragma unroll 4
    for (int it = 0; it < 16; ++it) {
        const int s = it * 4 + wid;              // wave-uniform slice
        const float* a = &As[s * 12];
        const float fz = (float)s * ST_RATIO;

        float x = fmaf(a[0], fh, fmaf(a[1], fw, fmaf(a[2],  fz, a[3])));
        float y = fmaf(a[4], fh, fmaf(a[5], fw, fmaf(a[6],  fz, a[7])));
        float z = fmaf(a[8], fh, fmaf(a[9], fw, fmaf(a[10], fz, a[11])));

        x = fminf(fmaxf(x, 0.0f), (float)(H - 1));
        y = fminf(fmaxf(y, 0.0f), (float)(W - 1));
        z = fminf(fmaxf(z, 0.0f), (float)(D - 1));

        const float flx = floorf(x), fly = floorf(y), flz = floorf(z);
        const float dx = x - flx, dy = y - fly, dz = z - flz;
        const int ix0 = (int)flx, iy0 = (int)fly, iz0 = (int)flz;
        const int ix1 = min(ix0 + 1, H - 1);
        const int iy1 = min(iy0 + 1, W - 1);
        const int iz1 = min(iz0 + 1, D - 1);

        // volT index: ((ix)*D + iz)*W + iy  -- iy fastest (contiguous per wave)
        const __half* p00 = vb + (ix0 * D + iz0) * W;
        const __half* p01 = vb + (ix0 * D + iz1) * W;
        const __half* p10 = vb + (ix1 * D + iz0) * W;
        const __half* p11 = vb + (ix1 * D + iz1) * W;

        const float v000 = __half2float(p00[iy0]), v001 = __half2float(p00[iy1]);
        const float v010 = __half2float(p01[iy0]), v011 = __half2float(p01[iy1]);
        const float v100 = __half2float(p10[iy0]), v101 = __half2float(p10[iy1]);
        const float v110 = __half2float(p11[iy0]), v111 = __half2float(p11[iy1]);

        // lerp over y, then z, then x
        const float c00 = fmaf(dy, v001 - v000, v000);
        const float c01 = fmaf(dy, v011 - v010, v010);
        const float c10 = fmaf(dy, v101 - v100, v100);
        const float c11 = fmaf(dy, v111 - v110, v110);
        const float c0  = fmaf(dz, c01 - c00, c00);
        const float c1  = fmaf(dz, c11 - c10, c10);
        outT[lane][s]   = fmaf(dx, c1 - c0, c0);
    }
    __syncthreads();

    // coalesced write-out: lanes along s
    const int s_out = lane;
#pragma unroll
    for (int r = 0; r < 16; ++r) {
        const int hw_off = wid + 4 * r;
        out[((size_t)(b * (H * W) + hw0 + hw_off)) * S + s_out] = outT[hw_off][s_out];
    }
}

// ---------------------------------------------------------------------------
// Fallback (R1 kernel) if d_ws is too small for the fp16 transposed volume.
// ---------------------------------------------------------------------------
__global__ __launch_bounds__(256) void v2s_fallback(
    const float* __restrict__ vol, const float* __restrict__ trf,
    float* __restrict__ out)
{
    __shared__ float As[S * 13];
    const int pos0 = blockIdx.x * 4;
    const int b = pos0 / (H * W);
    const float* tb = trf + (size_t)b * S * 12;
    for (int e = threadIdx.x; e < S * 12; e += 256) {
        int s = e / 12, j = e - s * 12;
        float v = tb[e];
        if ((j & 3) == (j >> 2)) v += 1.0f;
        As[s * 13 + j] = v;
    }
    __syncthreads();
    const int s   = threadIdx.x & 63;
    const int pos = pos0 + (threadIdx.x >> 6);
    const int hw  = pos % (H * W);
    const int h   = hw / W;
    const int w   = hw - h * W;
    const float* a = &As[s * 13];
    const float fh = (float)h, fw = (float)w, fz = (float)s * ST_RATIO;
    float x = fmaf(a[0], fh, fmaf(a[1], fw, fmaf(a[2],  fz, a[3])));
    float y = fmaf(a[4], fh, fmaf(a[5], fw, fmaf(a[6],  fz, a[7])));
    float z = fmaf(a[8], fh, fmaf(a[9], fw, fmaf(a[10], fz, a[11])));
    x = fminf(fmaxf(x, 0.0f), (float)(H - 1));
    y = fminf(fmaxf(y, 0.0f), (float)(W - 1));
    z = fminf(fmaxf(z, 0.0f), (float)(D - 1));
    const float flx = floorf(x), fly = floorf(y), flz = floorf(z);
    const float dx = x - flx, dy = y - fly, dz = z - flz;
    const int ix0 = (int)flx, iy0 = (int)fly, iz0 = (int)flz;
    const int ix1 = min(ix0 + 1, H - 1);
    const int iy1 = min(iy0 + 1, W - 1);
    const int iz1 = min(iz0 + 1, D - 1);
    const float* vb  = vol + (size_t)b * (H * W * D);
    const float* p00 = vb + (ix0 * W + iy0) * D;
    const float* p01 = vb + (ix0 * W + iy1) * D;
    const float* p10 = vb + (ix1 * W + iy0) * D;
    const float* p11 = vb + (ix1 * W + iy1) * D;
    const float v000 = p00[iz0], v001 = p00[iz1];
    const float v010 = p01[iz0], v011 = p01[iz1];
    const float v100 = p10[iz0], v101 = p10[iz1];
    const float v110 = p11[iz0], v111 = p11[iz1];
    const float c00 = fmaf(dz, v001 - v000, v000);
    const float c01 = fmaf(dz, v011 - v010, v010);
    const float c10 = fmaf(dz, v101 - v100, v100);
    const float c11 = fmaf(dz, v111 - v110, v110);
    const float c0  = fmaf(dy, c01 - c00, c00);
    const float c1  = fmaf(dy, c11 - c10, c10);
    out[(size_t)pos * S + s] = fmaf(dx, c1 - c0, c0);
}

extern "C" void kernel_launch(void* const* d_in, const int* in_sizes, int n_in,
                              void* d_out, int out_size, void* d_ws, size_t ws_size,
                              hipStream_t stream) {
    const float* vol = (const float*)d_in[0];
    const float* trf = (const float*)d_in[1];
    float* out = (float*)d_out;

    const size_t volT_bytes = (size_t)B * H * D * W * sizeof(__half);  // 39.3 MB
    if (ws_size >= volT_bytes) {
        __half* volT = (__half*)d_ws;
        v2s_transpose<<<B * H * 5 * 3, 256, 0, stream>>>(vol, volT);
        v2s_main<<<(B * H * W) / 64, 256, 0, stream>>>(volT, trf, out);
    } else {
        v2s_fallback<<<(B * H * W) / 4, 256, 0, stream>>>(vol, trf, out);
    }
}